// Round 18
// baseline (152.524 us; speedup 1.0000x reference)
//
#include <hip/hip_runtime.h>

#define NPTS   20480
#define KNN    16
#define NSLOT  20          // truncated-key list (17 needed + tie margin)
#define NCH    32
#define NFEAT  64
#define BN_EPS 1e-5f
#define AMB_EPS 2.6e-7f    // 1 quantum of d2 = ulp(sqq+sqc ~ 2.0)
#define GH     16          // grid cells per axis
#define NCELL  (GH*GH*GH)
#define RHO0   2
#define NBLK   (NPTS / 256)   // 80 prep blocks
#define MLPBLK 640            // BN partial blocks (32 pts each) — layout unchanged
#define MLPGRID (NPTS / 64)   // 320 MLP compute blocks (64 pts each)
#define NGRP   (NPTS / 64)    // 320 query groups
#define NWAVE  4              // waves per knn_fused block (256 threads)
#define NPAR   4              // candidate parity split
#define NZERO  (2 * NCELL + NGRP)   // cnt + cursor + flag

__device__ __forceinline__ unsigned med3u(unsigned a, unsigned b, unsigned c) {
    unsigned d;
    asm("v_med3_u32 %0, %1, %2, %3" : "=v"(d) : "v"(a), "v"(b), "v"(c));
    return d;
}

// Reference-f32 expansion distance (V1 FMA-chain dot — validated r5-r17).
__device__ __forceinline__ float ref_d2_raw(float qx, float qy, float qz, float sqq,
                                            float cx, float cy, float cz, float sqc) {
    float dot = fmaf(qz, cz, fmaf(qy, cy, __fmul_rn(qx, cx)));
    float t   = __fadd_rn(sqq, sqc);
    return fmaf(-2.0f, dot, t);             // single rounding, == fl(t - 2*dot)
}
__device__ __forceinline__ float ref_d2(float qx, float qy, float qz, float sqq,
                                        float cx, float cy, float cz, float sqc) {
    return fmaxf(ref_d2_raw(qx, qy, qz, sqq, cx, cy, cz, sqc), 1e-12f);
}

// Scan slots [c0,c1) with stride STEP: insert truncated keys into b[NSLOT].
template <int STEP>
__device__ __forceinline__ void scan_range(const float4* __restrict__ spts,
                                           int c0, int c1, float4 qp, int self,
                                           unsigned* b) {
    for (int c = c0; c < c1; c += STEP) {
        float4 s = spts[c];
        float d2 = ref_d2_raw(qp.x, qp.y, qp.z, qp.w, s.x, s.y, s.z, s.w);
        unsigned key = (__float_as_uint(d2) & 0xFFFF8000u) | (unsigned)c;
        if (c == self) key = 0xFFFFFFFFu;
#pragma unroll
        for (int s2 = NSLOT - 1; s2 >= 1; --s2) b[s2] = med3u(key, b[s2 - 1], b[s2]);
        b[0] = min(key, b[0]);
    }
}

// Zero cnt+cursor+flag.
__global__ __launch_bounds__(256) void zero_cells(int* __restrict__ p) {
    int i = blockIdx.x * 256 + threadIdx.x;
    if (i < NZERO) p[i] = 0;
}

// ---------------------------------------------------------------------------
// blocks [0,NBLK): coord prep + cell count.
// blocks [NBLK,NBLK+MLPGRID): MLP hidden for 64 points/block, wave-uniform w1
// rows (validated r17: removes gather serialization). Bit-exact vs r16.
// ---------------------------------------------------------------------------
__global__ __launch_bounds__(256) void prep_mlp(const float* __restrict__ coord,
                                                float4* __restrict__ pts4,
                                                int* __restrict__ pcell,
                                                int* __restrict__ cnt,
                                                const float* __restrict__ feat,
                                                const float* __restrict__ w1,
                                                const float* __restrict__ b1,
                                                float* __restrict__ h_ws,
                                                float* __restrict__ partials) {
    __shared__ float sfeat[64 * 65];          // 16.6 KB, pad-65: conflict-free
    __shared__ float hpart[4][64][NCH + 1];   // 33.8 KB, pad-33: conflict-free
    const int tid = threadIdx.x;

    if (blockIdx.x < NBLK) {
        int i = blockIdx.x * 256 + tid;
        float x = coord[3 * i + 0], y = coord[3 * i + 1], z = coord[3 * i + 2];
        float sq = __fadd_rn(__fadd_rn(__fmul_rn(x, x), __fmul_rn(y, y)),
                             __fmul_rn(z, z));
        pts4[i] = make_float4(x, y, z, sq);
        int ix = min(GH - 1, max(0, (int)(x * (float)GH)));
        int iy = min(GH - 1, max(0, (int)(y * (float)GH)));
        int iz = min(GH - 1, max(0, (int)(z * (float)GH)));
        int cell = (iz * GH + iy) * GH + ix;
        pcell[i] = cell;
        atomicAdd(&cnt[cell], 1);
        return;
    }
    const int blk  = blockIdx.x - NBLK;       // 64 points: [blk*64, blk*64+64)
    const int lane = tid & 63;
    const int wv   = __builtin_amdgcn_readfirstlane(tid >> 6);

    // ---- stage feat coalesced: 4096 floats = 1024 float4
    const float4* fsrc = reinterpret_cast<const float4*>(feat + (size_t)blk * 64 * NFEAT);
#pragma unroll
    for (int it = 0; it < 4; ++it) {
        float4 v = fsrc[it * 256 + tid];
        int f = it * 1024 + tid * 4;
        int pt = f >> 6, c = f & 63;
        sfeat[pt * 65 + c + 0] = v.x;
        sfeat[pt * 65 + c + 1] = v.y;
        sfeat[pt * 65 + c + 2] = v.z;
        sfeat[pt * 65 + c + 3] = v.w;
    }
    __syncthreads();

    // ---- wave wv: channels [16wv,16wv+16) for point=lane; uniform w1 rows.
    float hA[NCH], hB[NCH];
#pragma unroll
    for (int j = 0; j < NCH; ++j) { hA[j] = 0.f; hB[j] = 0.f; }
    const int cbase = wv * 16;
#pragma unroll
    for (int cc = 0; cc < 16; ++cc) {
        int c = cbase + cc;
        float fv = sfeat[lane * 65 + c];
        const float* wrow = w1 + c * NCH;     // wave-uniform -> scalar loads
        if (cc < 8) {
#pragma unroll
            for (int j = 0; j < NCH; ++j) hA[j] = fmaf(fv, wrow[j], hA[j]);
        } else {
#pragma unroll
            for (int j = 0; j < NCH; ++j) hB[j] = fmaf(fv, wrow[j], hB[j]);
        }
    }
#pragma unroll
    for (int j = 0; j < NCH; ++j) hpart[wv][lane][j] = hA[j] + hB[j]; // xor1 step
    __syncthreads();
    if (wv != 0) return;

    // ---- wave 0: final combine (bit-matches r16's xor2+xor4 tree)
    float h[NCH];
#pragma unroll
    for (int j = 0; j < NCH; ++j) {
        float q0 = hpart[0][lane][j], q1 = hpart[1][lane][j];
        float q2 = hpart[2][lane][j], q3 = hpart[3][lane][j];
        h[j] = (q0 + q1) + (q2 + q3);
        h[j] = h[j] + b1[j];
    }
    float4* hd = reinterpret_cast<float4*>(h_ws + ((size_t)blk * 64 + lane) * NCH);
#pragma unroll
    for (int j4 = 0; j4 < NCH / 4; ++j4)
        hd[j4] = make_float4(h[4 * j4], h[4 * j4 + 1], h[4 * j4 + 2], h[4 * j4 + 3]);

    // ---- BN partials, r16 bit order (per-8 butterfly, ((T0+T1)+T2)+T3)
    float myS0 = 0.f, myQ0 = 0.f, myS1 = 0.f, myQ1 = 0.f;
#pragma unroll
    for (int j = 0; j < NCH; ++j) {
        float v = h[j], vv = h[j] * h[j];
        v += __shfl_xor(v, 1, 64);  vv += __shfl_xor(vv, 1, 64);
        v += __shfl_xor(v, 2, 64);  vv += __shfl_xor(vv, 2, 64);
        v += __shfl_xor(v, 4, 64);  vv += __shfl_xor(vv, 4, 64);
        float t0 = __shfl(v, 0, 64),  t1 = __shfl(v, 8, 64);
        float t2 = __shfl(v, 16, 64), t3 = __shfl(v, 24, 64);
        float t4 = __shfl(v, 32, 64), t5 = __shfl(v, 40, 64);
        float t6 = __shfl(v, 48, 64), t7 = __shfl(v, 56, 64);
        float u0 = __shfl(vv, 0, 64),  u1 = __shfl(vv, 8, 64);
        float u2 = __shfl(vv, 16, 64), u3 = __shfl(vv, 24, 64);
        float u4 = __shfl(vv, 32, 64), u5 = __shfl(vv, 40, 64);
        float u6 = __shfl(vv, 48, 64), u7 = __shfl(vv, 56, 64);
        float s0 = ((t0 + t1) + t2) + t3;
        float s1 = ((t4 + t5) + t6) + t7;
        float q0 = ((u0 + u1) + u2) + u3;
        float q1 = ((u4 + u5) + u6) + u7;
        if (lane == j) { myS0 = s0; myQ0 = q0; myS1 = s1; myQ1 = q1; }
    }
    if (lane < NCH) {
        partials[(size_t)(2 * blk) * 64 + lane]            = myS0;
        partials[(size_t)(2 * blk) * 64 + NCH + lane]      = myQ0;
        partials[(size_t)(2 * blk + 1) * 64 + lane]        = myS1;
        partials[(size_t)(2 * blk + 1) * 64 + NCH + lane]  = myQ1;
    }
}

// ---------------------------------------------------------------------------
// blocks 0-79: in-LDS cell prefix (pure function of cnt) + scatter.
// block 80:   wave 0 = BN reduce -> mustats; wave 1 = global startArr write.
// ---------------------------------------------------------------------------
__global__ __launch_bounds__(256) void scatter_pref(const float4* __restrict__ pts4,
                                                    const int* __restrict__ pcell,
                                                    const int* __restrict__ cnt,
                                                    int* __restrict__ cursor,
                                                    float4* __restrict__ spts,
                                                    int* __restrict__ sidx,
                                                    const float* __restrict__ partials,
                                                    float* __restrict__ mustats,
                                                    int* __restrict__ startArr) {
    const int tid = threadIdx.x;
    const int lane = tid & 63;
    if (blockIdx.x < NBLK) {
        __shared__ int chunks[256];
        __shared__ int sstart[NCELL];            // 16 KB
        int local[16];
        int base = tid * 16, s = 0;
#pragma unroll
        for (int i = 0; i < 16; ++i) { local[i] = cnt[base + i]; s += local[i]; }
        chunks[tid] = s;
        __syncthreads();
        if (tid < 64) {
            int a0 = chunks[4 * tid + 0], a1 = chunks[4 * tid + 1];
            int a2 = chunks[4 * tid + 2], a3 = chunks[4 * tid + 3];
            int tot = a0 + a1 + a2 + a3;
            int inc = tot;
#pragma unroll
            for (int d = 1; d < 64; d <<= 1) {
                int t = __shfl_up(inc, d, 64);
                if (lane >= d) inc += t;
            }
            int excl = inc - tot;
            chunks[4 * tid + 0] = excl;
            chunks[4 * tid + 1] = excl + a0;
            chunks[4 * tid + 2] = excl + a0 + a1;
            chunks[4 * tid + 3] = excl + a0 + a1 + a2;
        }
        __syncthreads();
        int acc = chunks[tid];
#pragma unroll
        for (int i = 0; i < 16; ++i) { sstart[base + i] = acc; acc += local[i]; }
        __syncthreads();
        int i = blockIdx.x * 256 + tid;
        int c = pcell[i];
        int slot = sstart[c] + atomicAdd(&cursor[c], 1);
        spts[slot] = pts4[i];
        sidx[slot] = i;
        return;
    }
    // block 80
    if (tid < 64) {           // wave 0: BN reduce (f64)
        double s = 0.0;
        for (int bk = 0; bk < MLPBLK; ++bk) s += (double)partials[bk * 64 + lane];
        __shared__ double smu[NCH];
        if (lane < NCH) { double mu = s / (double)NPTS; smu[lane] = mu; mustats[lane] = (float)mu; }
        __syncthreads();
        if (lane >= NCH) {
            int jj = lane - NCH;
            double var = s / (double)NPTS - smu[jj] * smu[jj];   // biased, torch BN
            mustats[lane] = (float)(1.0 / sqrt(var + (double)BN_EPS));
        }
    } else if (tid < 128) {   // wave 1: global exclusive prefix -> startArr
        __syncthreads();      // match wave 0's barrier
        int base = lane * (NCELL / 64);
        int tot = 0;
        for (int i = 0; i < NCELL / 64; ++i) tot += cnt[base + i];
        int inc = tot;
#pragma unroll
        for (int d = 1; d < 64; d <<= 1) {
            int t = __shfl_up(inc, d, 64);
            if (lane >= d) inc += t;
        }
        int acc = inc - tot;
        for (int i = 0; i < NCELL / 64; ++i) { startArr[base + i] = acc; acc += cnt[base + i]; }
        if (lane == 63) startArr[NCELL] = acc;
    } else {
        __syncthreads();
    }
}

// f64 stats over a 16-neighbor set (slot indices into spts) — validated r5-r17.
__device__ void knn_stats(const float4* __restrict__ spts,
                          double qx, double qy, double qz,
                          const int* idx, const float* d2s,
                          double* den_out, double* lin_out) {
    double sx = 0, sy = 0, sz = 0;
    double sxx = 0, syy = 0, szz = 0, sxy = 0, sxz = 0, syz = 0;
    double dsum = 0;
#pragma unroll
    for (int s = 0; s < KNN; ++s) {
        float4 cp = spts[idx[s]];
        double ax = (double)cp.x - qx;
        double ay = (double)cp.y - qy;
        double az = (double)cp.z - qz;
        sx += ax; sy += ay; sz += az;
        sxx += ax * ax; syy += ay * ay; szz += az * az;
        sxy += ax * ay; sxz += ax * az; syz += ay * az;
        dsum += (double)sqrtf(d2s[s]);
    }
    const double invK  = 1.0 / KNN;
    const double invK1 = 1.0 / (KNN - 1);
    double mxx = sx * invK, myy = sy * invK, mzz = sz * invK;
    double cxx = (sxx - (double)KNN * mxx * mxx) * invK1;
    double cyy = (syy - (double)KNN * myy * myy) * invK1;
    double czz = (szz - (double)KNN * mzz * mzz) * invK1;
    double cxy = (sxy - (double)KNN * mxx * myy) * invK1;
    double cxz = (sxz - (double)KNN * mxx * mzz) * invK1;
    double cyz = (syz - (double)KNN * myy * mzz) * invK1;

    double T  = cxx + cyy + czz;
    double qq = T / 3.0;
    double b00 = cxx - qq, b11 = cyy - qq, b22 = czz - qq;
    double p2 = b00 * b00 + b11 * b11 + b22 * b22
              + 2.0 * (cxy * cxy + cxz * cxz + cyz * cyz);
    double lmax;
    if (p2 <= 1e-30) {
        lmax = qq;
    } else {
        double p = sqrt(p2 / 6.0);
        double detB = b00 * (b11 * b22 - cyz * cyz)
                    - cxy * (cxy * b22 - cyz * cxz)
                    + cxz * (cxy * cyz - b11 * cxz);
        double r = detB / (2.0 * p * p * p);
        r = fmin(1.0, fmax(-1.0, r));
        double phi = acos(r) / 3.0;
        lmax = qq + 2.0 * p * cos(phi);
    }
    *lin_out = (2.0 * lmax - T) / (T + 1e-6);
    *den_out = 1.0 / (dsum * invK + 1e-6);
}

// ---------------------------------------------------------------------------
// Fused KNN scan+finalize: 1280 blocks x 256 threads. Block (4g+par) scans
// candidate class (c&3)==par for group g (4 waves, rows r%4), tree-merges to
// a quarter top-20, publishes it, and bumps flag[g] (per-GROUP flag: max
// 4-way contention — r12's failure was a single 720-way done-counter, not
// this pattern). The 4th finisher merges the 3 partner lists (top-20 of
// distinct keys is insert-order-invariant -> bit-identical) and runs the
// validated finalize + head inline, overlapping remaining scans.
// ---------------------------------------------------------------------------
__global__ __launch_bounds__(256) void knn_fused(
    const float4* __restrict__ spts, const int* __restrict__ sidx,
    const int* __restrict__ start,   unsigned* __restrict__ quarterkeys,
    int* __restrict__ flag,
    const float* __restrict__ h_ws,  const float* __restrict__ gamma,
    const float* __restrict__ beta,  const float* __restrict__ w2,
    const float* __restrict__ b2,    const float* __restrict__ mustats,
    float* __restrict__ out) {
    __shared__ unsigned keysh[NWAVE * NSLOT][64];      // 20 KB
    const int lane = threadIdx.x & 63;
    const int wv   = threadIdx.x >> 6;
    const int g    = blockIdx.x >> 2;
    const int par  = blockIdx.x & 3;
    const int slot = g * 64 + lane;
    const float4 qp = spts[slot];
    const int ix = min(GH - 1, max(0, (int)(qp.x * (float)GH)));
    const int iy = min(GH - 1, max(0, (int)(qp.y * (float)GH)));
    const int iz = min(GH - 1, max(0, (int)(qp.z * (float)GH)));

    unsigned b[NSLOT];
#pragma unroll
    for (int s = 0; s < NSLOT; ++s) b[s] = 0xFFFFFFFFu;
    {
        const int zlo = max(0, iz - RHO0), zhi = min(GH - 1, iz + RHO0);
        const int ylo = max(0, iy - RHO0), yhi = min(GH - 1, iy + RHO0);
        const int xlo = max(0, ix - RHO0), xhi = min(GH - 1, ix + RHO0);
        int r = 0;
        for (int cz = zlo; cz <= zhi; ++cz)
            for (int cy = ylo; cy <= yhi; ++cy) {
                if ((r & (NWAVE - 1)) == wv) {
                    const int rb = (cz * GH + cy) * GH;
                    int c0 = start[rb + xlo];
                    int c1 = start[rb + xhi + 1];
                    scan_range<NPAR>(spts, c0 + ((par - c0) & (NPAR - 1)), c1,
                                     qp, slot, b);
                }
                ++r;
            }
    }
#pragma unroll
    for (int s = 0; s < NSLOT; ++s) keysh[wv * NSLOT + s][lane] = b[s];
    __syncthreads();

    // ---- merge level 1: waves 0-1 merge lists {2w, 2w+1}
    unsigned m[NSLOT];
    if (wv < 2) {
#pragma unroll
        for (int s = 0; s < NSLOT; ++s) m[s] = 0xFFFFFFFFu;
        for (int p2 = 2 * wv; p2 <= 2 * wv + 1; ++p2) {
#pragma unroll
            for (int s = 0; s < NSLOT; ++s) {
                unsigned key = keysh[p2 * NSLOT + s][lane];
#pragma unroll
                for (int t = NSLOT - 1; t >= 1; --t) m[t] = med3u(key, m[t - 1], m[t]);
                m[0] = min(key, m[0]);
            }
        }
    }
    __syncthreads();
    if (wv < 2) {
#pragma unroll
        for (int s = 0; s < NSLOT; ++s) keysh[wv * NSLOT + s][lane] = m[s];
    }
    __syncthreads();
    if (wv != 0) return;

    // ---- merge level 2: wave 0 merges lists 0-1 -> own quarter-list in m
#pragma unroll
    for (int s = 0; s < NSLOT; ++s) m[s] = 0xFFFFFFFFu;
    for (int p2 = 0; p2 < 2; ++p2) {
#pragma unroll
        for (int s = 0; s < NSLOT; ++s) {
            unsigned key = keysh[p2 * NSLOT + s][lane];
#pragma unroll
            for (int t = NSLOT - 1; t >= 1; --t) m[t] = med3u(key, m[t - 1], m[t]);
            m[0] = min(key, m[0]);
        }
    }

    // ---- publish quarter-list; 4th finisher continues (per-group flag)
    unsigned* myh = quarterkeys + (size_t)(g * NPAR + par) * NSLOT * 64;
#pragma unroll
    for (int s = 0; s < NSLOT; ++s) myh[s * 64 + lane] = m[s];
    __threadfence();
    int old = 0;
    if (lane == 0) old = atomicAdd(&flag[g], 1);
    old = __shfl(old, 0, 64);
    if (old != NPAR - 1) return;
    __threadfence();                          // acquire partners' writes

    for (int p2 = 0; p2 < NPAR; ++p2) {
        if (p2 == par) continue;
        const unsigned* ph = quarterkeys + (size_t)(g * NPAR + p2) * NSLOT * 64;
#pragma unroll
        for (int s = 0; s < NSLOT; ++s) {
            unsigned key = ph[s * 64 + lane];
#pragma unroll
            for (int t = NSLOT - 1; t >= 1; --t) m[t] = med3u(key, m[t - 1], m[t]);
            m[0] = min(key, m[0]);
        }
    }

    // ---- coverage check; rare per-lane expansion rescan (full stride)
    const float h = 1.0f / (float)GH;
    int rho = RHO0;
    for (;;) {
        float b16f = __uint_as_float(m[16] & 0xFFFF8000u);  // NaN if unfilled
        float cov  = (float)(rho * rho) * (h * h);
        bool ok = (fmaf(b16f, 0.00390625f, b16f) + 1e-6f) <= cov;
        if (__all(ok) || rho >= GH - 1) break;
        ++rho;
        if (!ok) {
#pragma unroll
            for (int s = 0; s < NSLOT; ++s) m[s] = 0xFFFFFFFFu;
            const int zlo = max(0, iz - rho), zhi = min(GH - 1, iz + rho);
            const int ylo = max(0, iy - rho), yhi = min(GH - 1, iy + rho);
            const int xlo = max(0, ix - rho), xhi = min(GH - 1, ix + rho);
            for (int cz = zlo; cz <= zhi; ++cz)
                for (int cy = ylo; cy <= yhi; ++cy) {
                    const int rb = (cz * GH + cy) * GH;
                    scan_range<1>(spts, start[rb + xlo], start[rb + xhi + 1],
                                  qp, slot, m);
                }
        }
    }

    // ---- exact re-rank: top KNN+1 u64 keys (full d2 bits << 32 | SLOT index)
    unsigned long long gk[KNN + 1];
#pragma unroll
    for (int s = 0; s < KNN + 1; ++s) gk[s] = ~0ull;
#pragma unroll
    for (int s = 0; s < NSLOT; ++s) {
        unsigned bs = m[s];
        int cs = min((int)(bs & 0x7FFFu), NPTS - 1);
        float4 cp = spts[cs];
        float d2 = ref_d2(qp.x, qp.y, qp.z, qp.w, cp.x, cp.y, cp.z, cp.w);
        unsigned long long kk =
            ((unsigned long long)__float_as_uint(d2) << 32) | (unsigned)cs;
        if (bs == 0xFFFFFFFFu) kk = ~0ull;
#pragma unroll
        for (int t = KNN; t >= 1; --t) {
            unsigned long long mn = (kk < gk[t]) ? kk : gk[t];
            gk[t] = (gk[t - 1] > mn) ? gk[t - 1] : mn;
        }
        gk[0] = (kk < gk[0]) ? kk : gk[0];
    }

    int   idxA[KNN];
    float d2A[KNN];
#pragma unroll
    for (int s = 0; s < KNN; ++s) {
        idxA[s] = (int)(gk[s] & 0xFFFFFFFFull);
        d2A[s]  = __uint_as_float((unsigned)(gk[s] >> 32));
    }
    float d16 = d2A[KNN - 1];
    float d17 = __uint_as_float((unsigned)(gk[KNN] >> 32));
    bool amb = (__fsub_rn(d17, d16) <= AMB_EPS);

    const double qx = (double)qp.x, qy = (double)qp.y, qz = (double)qp.z;
    double denA, linA;
    knn_stats(spts, qx, qy, qz, idxA, d2A, &denA, &linA);
    double den = denA, lin_d = linA;
    if (amb) {
        idxA[KNN - 1] = (int)(gk[KNN] & 0xFFFFFFFFull);
        d2A[KNN - 1]  = d17;
        double denB, linB;
        knn_stats(spts, qx, qy, qz, idxA, d2A, &denB, &linB);
        den = 0.5 * (denA + denB);
        lin_d = 0.5 * (linA + linB);
    }
    float dens = (float)den;
    float lin  = (float)lin_d;

    // ---- per-point head from precomputed h: BN + ReLU + GEMV + softmax
    const int qi = sidx[slot];
    float hh[NCH];
    const float4* h4 = reinterpret_cast<const float4*>(h_ws + (size_t)qi * NCH);
#pragma unroll
    for (int j4 = 0; j4 < NCH / 4; ++j4) {
        float4 v = h4[j4];
        hh[j4 * 4 + 0] = v.x; hh[j4 * 4 + 1] = v.y;
        hh[j4 * 4 + 2] = v.z; hh[j4 * 4 + 3] = v.w;
    }
    float l0 = b2[0], l1 = b2[1], l2 = b2[2];
#pragma unroll
    for (int j = 0; j < NCH; ++j) {
        float xn = (hh[j] - mustats[j]) * mustats[NCH + j] * gamma[j] + beta[j];
        xn = fmaxf(xn, 0.f);
        l0 = fmaf(xn, w2[j * 3 + 0], l0);
        l1 = fmaf(xn, w2[j * 3 + 1], l1);
        l2 = fmaf(xn, w2[j * 3 + 2], l2);
    }
    float mx = fmaxf(l0, fmaxf(l1, l2));
    float e0 = expf(l0 - mx), e1 = expf(l1 - mx), e2 = expf(l2 - mx);
    float is = 1.f / (e0 + e1 + e2);
    float p0 = e0 * is, p1 = e1 * is, p2v = e2 * is;

    float tower = (dens * 2.f + p0) * (1.f / 3.f);
    float back  = (fmaxf(1.f - lin, 1.f - dens) + p1) * (1.f / 3.f);
    float line  = (lin * 2.f + p2v) * (1.f / 3.f);
    float gxy = fmaf(tower, 0.05f, fmaf(back, 0.20f, fmaf(line, 0.10f, 1e-6f)));
    float gz  = fmaf(tower, 0.05f, fmaf(back, 0.20f, fmaf(line, 0.50f, 1e-6f)));
    out[3 * qi + 0] = gxy;
    out[3 * qi + 1] = gxy;
    out[3 * qi + 2] = gz;
}

extern "C" void kernel_launch(void* const* d_in, const int* in_sizes, int n_in,
                              void* d_out, int out_size, void* d_ws, size_t ws_size,
                              hipStream_t stream) {
    const float* feat  = (const float*)d_in[0];
    const float* coord = (const float*)d_in[1];
    // d_in[2] = batch (all zeros) — unused
    const float* w1    = (const float*)d_in[3];
    const float* b1    = (const float*)d_in[4];
    const float* gamma = (const float*)d_in[5];
    const float* beta  = (const float*)d_in[6];
    const float* w2    = (const float*)d_in[7];
    const float* b2    = (const float*)d_in[8];
    float* out = (float*)d_out;

    // workspace layout (~10.4 MB); cnt/cursor/flag contiguous -> one zero pass
    float4* pts4   = (float4*)d_ws;                     // NPTS
    float4* spts   = pts4 + NPTS;                       // NPTS
    int* sidx      = (int*)(spts + NPTS);               // NPTS
    int* pcell     = sidx + NPTS;                       // NPTS
    int* cnt       = pcell + NPTS;                      // NCELL
    int* cursor    = cnt + NCELL;                       // NCELL
    int* flag      = cursor + NCELL;                    // NGRP
    int* startArr  = flag + NGRP;                       // NCELL+1 (+pad)
    unsigned* quarterkeys = (unsigned*)(startArr + NCELL + 8); // NPAR*NGRP*NSLOT*64
    float* partials  = (float*)(quarterkeys + (size_t)NPAR * NGRP * NSLOT * 64);
    float* mustats   = partials + MLPBLK * 64;          // 64
    float* h_ws      = mustats + 64;                    // NPTS*NCH

    zero_cells<<<(NZERO + 255) / 256, 256, 0, stream>>>(cnt);
    prep_mlp<<<NBLK + MLPGRID, 256, 0, stream>>>(coord, pts4, pcell, cnt,
                                                 feat, w1, b1, h_ws, partials);
    scatter_pref<<<NBLK + 1, 256, 0, stream>>>(pts4, pcell, cnt, cursor,
                                               spts, sidx, partials, mustats,
                                               startArr);
    knn_fused<<<NPAR * NGRP, 256, 0, stream>>>(spts, sidx, startArr, quarterkeys,
                                               flag, h_ws, gamma, beta, w2, b2,
                                               mustats, out);
}

// Round 19
// 86.861 us; speedup vs baseline: 1.7559x; 1.7559x over previous
//
#include <hip/hip_runtime.h>

#define NPTS   20480
#define KNN    16
#define NSLOT  20          // truncated-key list (17 needed + tie margin)
#define NCH    32
#define NFEAT  64
#define BN_EPS 1e-5f
#define AMB_EPS 2.6e-7f    // 1 quantum of d2 = ulp(sqq+sqc ~ 2.0)
#define GH     16          // grid cells per axis
#define NCELL  (GH*GH*GH)
#define RHO0   2
#define NBLK   (NPTS / 256)   // 80 prep blocks
#define MLPBLK 640            // BN partial blocks (32 pts each) — layout unchanged
#define MLPGRID (NPTS / 64)   // 320 MLP compute blocks (64 pts each)
#define NGRP   (NPTS / 64)    // 320 query groups
#define NWAVE  4              // waves per knn_scan block (256 threads)
#define NPAR   4              // candidate parity split

__device__ __forceinline__ unsigned med3u(unsigned a, unsigned b, unsigned c) {
    unsigned d;
    asm("v_med3_u32 %0, %1, %2, %3" : "=v"(d) : "v"(a), "v"(b), "v"(c));
    return d;
}

// Reference-f32 expansion distance (V1 FMA-chain dot — validated r5-r17).
__device__ __forceinline__ float ref_d2_raw(float qx, float qy, float qz, float sqq,
                                            float cx, float cy, float cz, float sqc) {
    float dot = fmaf(qz, cz, fmaf(qy, cy, __fmul_rn(qx, cx)));
    float t   = __fadd_rn(sqq, sqc);
    return fmaf(-2.0f, dot, t);             // single rounding, == fl(t - 2*dot)
}
__device__ __forceinline__ float ref_d2(float qx, float qy, float qz, float sqq,
                                        float cx, float cy, float cz, float sqc) {
    return fmaxf(ref_d2_raw(qx, qy, qz, sqq, cx, cy, cz, sqc), 1e-12f);
}

// Scan slots [c0,c1) with stride STEP: insert truncated keys into b[NSLOT].
template <int STEP>
__device__ __forceinline__ void scan_range(const float4* __restrict__ spts,
                                           int c0, int c1, float4 qp, int self,
                                           unsigned* b) {
    for (int c = c0; c < c1; c += STEP) {
        float4 s = spts[c];
        float d2 = ref_d2_raw(qp.x, qp.y, qp.z, qp.w, s.x, s.y, s.z, s.w);
        unsigned key = (__float_as_uint(d2) & 0xFFFF8000u) | (unsigned)c;
        if (c == self) key = 0xFFFFFFFFu;
#pragma unroll
        for (int s2 = NSLOT - 1; s2 >= 1; --s2) b[s2] = med3u(key, b[s2 - 1], b[s2]);
        b[0] = min(key, b[0]);
    }
}

// Zero cnt+cursor (8192 ints).
__global__ __launch_bounds__(256) void zero_cells(int* __restrict__ p) {
    p[blockIdx.x * 256 + threadIdx.x] = 0;
}

// ---------------------------------------------------------------------------
// blocks [0,NBLK): coord prep + cell count.
// blocks [NBLK,NBLK+MLPGRID): MLP hidden for 64 points/block.
//   feat staged to LDS (coalesced, pad-65); wave w computes channels
//   [16w,16w+16) for all 64 points with WAVE-UNIFORM w1 rows (scalar loads,
//   no divergent gathers). Partial-sum tree and BN-partial order bit-exact.
// ---------------------------------------------------------------------------
__global__ __launch_bounds__(256) void prep_mlp(const float* __restrict__ coord,
                                                float4* __restrict__ pts4,
                                                int* __restrict__ pcell,
                                                int* __restrict__ cnt,
                                                const float* __restrict__ feat,
                                                const float* __restrict__ w1,
                                                const float* __restrict__ b1,
                                                float* __restrict__ h_ws,
                                                float* __restrict__ partials) {
    __shared__ float sfeat[64 * 65];          // 16.6 KB, pad-65: conflict-free
    __shared__ float hpart[4][64][NCH + 1];   // 33.8 KB, pad-33: conflict-free
    const int tid = threadIdx.x;

    if (blockIdx.x < NBLK) {
        int i = blockIdx.x * 256 + tid;
        float x = coord[3 * i + 0], y = coord[3 * i + 1], z = coord[3 * i + 2];
        float sq = __fadd_rn(__fadd_rn(__fmul_rn(x, x), __fmul_rn(y, y)),
                             __fmul_rn(z, z));
        pts4[i] = make_float4(x, y, z, sq);
        int ix = min(GH - 1, max(0, (int)(x * (float)GH)));
        int iy = min(GH - 1, max(0, (int)(y * (float)GH)));
        int iz = min(GH - 1, max(0, (int)(z * (float)GH)));
        int cell = (iz * GH + iy) * GH + ix;
        pcell[i] = cell;
        atomicAdd(&cnt[cell], 1);
        return;
    }
    const int blk  = blockIdx.x - NBLK;       // 64 points: [blk*64, blk*64+64)
    const int lane = tid & 63;
    const int wv   = __builtin_amdgcn_readfirstlane(tid >> 6);

    // ---- stage feat coalesced: 4096 floats = 1024 float4
    const float4* fsrc = reinterpret_cast<const float4*>(feat + (size_t)blk * 64 * NFEAT);
#pragma unroll
    for (int it = 0; it < 4; ++it) {
        float4 v = fsrc[it * 256 + tid];
        int f = it * 1024 + tid * 4;
        int pt = f >> 6, c = f & 63;
        sfeat[pt * 65 + c + 0] = v.x;
        sfeat[pt * 65 + c + 1] = v.y;
        sfeat[pt * 65 + c + 2] = v.z;
        sfeat[pt * 65 + c + 3] = v.w;
    }
    __syncthreads();

    // ---- wave wv: channels [16wv,16wv+16) for point=lane; uniform w1 rows.
    float hA[NCH], hB[NCH];
#pragma unroll
    for (int j = 0; j < NCH; ++j) { hA[j] = 0.f; hB[j] = 0.f; }
    const int cbase = wv * 16;
#pragma unroll
    for (int cc = 0; cc < 16; ++cc) {
        int c = cbase + cc;
        float fv = sfeat[lane * 65 + c];
        const float* wrow = w1 + c * NCH;     // wave-uniform -> scalar loads
        if (cc < 8) {
#pragma unroll
            for (int j = 0; j < NCH; ++j) hA[j] = fmaf(fv, wrow[j], hA[j]);
        } else {
#pragma unroll
            for (int j = 0; j < NCH; ++j) hB[j] = fmaf(fv, wrow[j], hB[j]);
        }
    }
#pragma unroll
    for (int j = 0; j < NCH; ++j) hpart[wv][lane][j] = hA[j] + hB[j]; // xor1 step
    __syncthreads();
    if (wv != 0) return;

    // ---- wave 0: final combine (bit-matches xor2+xor4 tree: (q0+q1)+(q2+q3))
    float h[NCH];
#pragma unroll
    for (int j = 0; j < NCH; ++j) {
        float q0 = hpart[0][lane][j], q1 = hpart[1][lane][j];
        float q2 = hpart[2][lane][j], q3 = hpart[3][lane][j];
        h[j] = (q0 + q1) + (q2 + q3);
        h[j] = h[j] + b1[j];
    }
    float4* hd = reinterpret_cast<float4*>(h_ws + ((size_t)blk * 64 + lane) * NCH);
#pragma unroll
    for (int j4 = 0; j4 < NCH / 4; ++j4)
        hd[j4] = make_float4(h[4 * j4], h[4 * j4 + 1], h[4 * j4 + 2], h[4 * j4 + 3]);

    // ---- BN partials, r16 bit order: per-8-point butterfly tree, then
    // ((T0+T1)+T2)+T3 per 32-point half; layout = 640 blocks of 32 points.
    float myS0 = 0.f, myQ0 = 0.f, myS1 = 0.f, myQ1 = 0.f;
#pragma unroll
    for (int j = 0; j < NCH; ++j) {
        float v = h[j], vv = h[j] * h[j];
        v += __shfl_xor(v, 1, 64);  vv += __shfl_xor(vv, 1, 64);
        v += __shfl_xor(v, 2, 64);  vv += __shfl_xor(vv, 2, 64);
        v += __shfl_xor(v, 4, 64);  vv += __shfl_xor(vv, 4, 64);
        float t0 = __shfl(v, 0, 64),  t1 = __shfl(v, 8, 64);
        float t2 = __shfl(v, 16, 64), t3 = __shfl(v, 24, 64);
        float t4 = __shfl(v, 32, 64), t5 = __shfl(v, 40, 64);
        float t6 = __shfl(v, 48, 64), t7 = __shfl(v, 56, 64);
        float u0 = __shfl(vv, 0, 64),  u1 = __shfl(vv, 8, 64);
        float u2 = __shfl(vv, 16, 64), u3 = __shfl(vv, 24, 64);
        float u4 = __shfl(vv, 32, 64), u5 = __shfl(vv, 40, 64);
        float u6 = __shfl(vv, 48, 64), u7 = __shfl(vv, 56, 64);
        float s0 = ((t0 + t1) + t2) + t3;
        float s1 = ((t4 + t5) + t6) + t7;
        float q0 = ((u0 + u1) + u2) + u3;
        float q1 = ((u4 + u5) + u6) + u7;
        if (lane == j) { myS0 = s0; myQ0 = q0; myS1 = s1; myQ1 = q1; }
    }
    if (lane < NCH) {
        partials[(size_t)(2 * blk) * 64 + lane]            = myS0;
        partials[(size_t)(2 * blk) * 64 + NCH + lane]      = myQ0;
        partials[(size_t)(2 * blk + 1) * 64 + lane]        = myS1;
        partials[(size_t)(2 * blk + 1) * 64 + NCH + lane]  = myQ1;
    }
}

// ---------------------------------------------------------------------------
// blocks 0-79: in-LDS cell prefix (pure function of cnt) + scatter.
// block 80:   wave 0 = BN reduce -> mustats; wave 1 = global startArr write.
// ---------------------------------------------------------------------------
__global__ __launch_bounds__(256) void scatter_pref(const float4* __restrict__ pts4,
                                                    const int* __restrict__ pcell,
                                                    const int* __restrict__ cnt,
                                                    int* __restrict__ cursor,
                                                    float4* __restrict__ spts,
                                                    int* __restrict__ sidx,
                                                    const float* __restrict__ partials,
                                                    float* __restrict__ mustats,
                                                    int* __restrict__ startArr) {
    const int tid = threadIdx.x;
    const int lane = tid & 63;
    if (blockIdx.x < NBLK) {
        __shared__ int chunks[256];
        __shared__ int sstart[NCELL];            // 16 KB
        int local[16];
        int base = tid * 16, s = 0;
#pragma unroll
        for (int i = 0; i < 16; ++i) { local[i] = cnt[base + i]; s += local[i]; }
        chunks[tid] = s;
        __syncthreads();
        if (tid < 64) {
            int a0 = chunks[4 * tid + 0], a1 = chunks[4 * tid + 1];
            int a2 = chunks[4 * tid + 2], a3 = chunks[4 * tid + 3];
            int tot = a0 + a1 + a2 + a3;
            int inc = tot;
#pragma unroll
            for (int d = 1; d < 64; d <<= 1) {
                int t = __shfl_up(inc, d, 64);
                if (lane >= d) inc += t;
            }
            int excl = inc - tot;
            chunks[4 * tid + 0] = excl;
            chunks[4 * tid + 1] = excl + a0;
            chunks[4 * tid + 2] = excl + a0 + a1;
            chunks[4 * tid + 3] = excl + a0 + a1 + a2;
        }
        __syncthreads();
        int acc = chunks[tid];
#pragma unroll
        for (int i = 0; i < 16; ++i) { sstart[base + i] = acc; acc += local[i]; }
        __syncthreads();
        int i = blockIdx.x * 256 + tid;
        int c = pcell[i];
        int slot = sstart[c] + atomicAdd(&cursor[c], 1);
        spts[slot] = pts4[i];
        sidx[slot] = i;
        return;
    }
    // block 80
    if (tid < 64) {           // wave 0: BN reduce (f64)
        double s = 0.0;
        for (int bk = 0; bk < MLPBLK; ++bk) s += (double)partials[bk * 64 + lane];
        __shared__ double smu[NCH];
        if (lane < NCH) { double mu = s / (double)NPTS; smu[lane] = mu; mustats[lane] = (float)mu; }
        __syncthreads();
        if (lane >= NCH) {
            int jj = lane - NCH;
            double var = s / (double)NPTS - smu[jj] * smu[jj];   // biased, torch BN
            mustats[lane] = (float)(1.0 / sqrt(var + (double)BN_EPS));
        }
    } else if (tid < 128) {   // wave 1: global exclusive prefix -> startArr
        __syncthreads();      // match wave 0's barrier
        int base = lane * (NCELL / 64);
        int tot = 0;
        for (int i = 0; i < NCELL / 64; ++i) tot += cnt[base + i];
        int inc = tot;
#pragma unroll
        for (int d = 1; d < 64; d <<= 1) {
            int t = __shfl_up(inc, d, 64);
            if (lane >= d) inc += t;
        }
        int acc = inc - tot;
        for (int i = 0; i < NCELL / 64; ++i) { startArr[base + i] = acc; acc += cnt[base + i]; }
        if (lane == 63) startArr[NCELL] = acc;
    } else {
        __syncthreads();
    }
}

// ---------------------------------------------------------------------------
// KNN scan: 1280 blocks x 256 threads (4 waves). Block quad (4g+par) covers
// group g with candidate class (c&3)==par. 4 waves scan rows r%4, 2-level
// tree merge -> quarter top-20 -> global quarterkeys. No fences — the kernel
// boundary is the barrier (r12/r18 lesson: per-block device fences are ~40x
// more expensive than one extra launch).
// ---------------------------------------------------------------------------
__global__ __launch_bounds__(256) void knn_scan(
    const float4* __restrict__ spts, const int* __restrict__ start,
    unsigned* __restrict__ quarterkeys) {
    __shared__ unsigned keysh[NWAVE * NSLOT][64];      // 20 KB
    const int lane = threadIdx.x & 63;
    const int wv   = threadIdx.x >> 6;
    const int g    = blockIdx.x >> 2;
    const int par  = blockIdx.x & 3;
    const int slot = g * 64 + lane;
    const float4 qp = spts[slot];
    const int ix = min(GH - 1, max(0, (int)(qp.x * (float)GH)));
    const int iy = min(GH - 1, max(0, (int)(qp.y * (float)GH)));
    const int iz = min(GH - 1, max(0, (int)(qp.z * (float)GH)));

    unsigned b[NSLOT];
#pragma unroll
    for (int s = 0; s < NSLOT; ++s) b[s] = 0xFFFFFFFFu;
    {
        const int zlo = max(0, iz - RHO0), zhi = min(GH - 1, iz + RHO0);
        const int ylo = max(0, iy - RHO0), yhi = min(GH - 1, iy + RHO0);
        const int xlo = max(0, ix - RHO0), xhi = min(GH - 1, ix + RHO0);
        int r = 0;
        for (int cz = zlo; cz <= zhi; ++cz)
            for (int cy = ylo; cy <= yhi; ++cy) {
                if ((r & (NWAVE - 1)) == wv) {
                    const int rb = (cz * GH + cy) * GH;
                    int c0 = start[rb + xlo];
                    int c1 = start[rb + xhi + 1];
                    scan_range<NPAR>(spts, c0 + ((par - c0) & (NPAR - 1)), c1,
                                     qp, slot, b);
                }
                ++r;
            }
    }
#pragma unroll
    for (int s = 0; s < NSLOT; ++s) keysh[wv * NSLOT + s][lane] = b[s];
    __syncthreads();

    // ---- merge level 1: waves 0-1 merge lists {2w, 2w+1}
    unsigned m[NSLOT];
    if (wv < 2) {
#pragma unroll
        for (int s = 0; s < NSLOT; ++s) m[s] = 0xFFFFFFFFu;
        for (int p2 = 2 * wv; p2 <= 2 * wv + 1; ++p2) {
#pragma unroll
            for (int s = 0; s < NSLOT; ++s) {
                unsigned key = keysh[p2 * NSLOT + s][lane];
#pragma unroll
                for (int t = NSLOT - 1; t >= 1; --t) m[t] = med3u(key, m[t - 1], m[t]);
                m[0] = min(key, m[0]);
            }
        }
    }
    __syncthreads();
    if (wv < 2) {
#pragma unroll
        for (int s = 0; s < NSLOT; ++s) keysh[wv * NSLOT + s][lane] = m[s];
    }
    __syncthreads();
    if (wv != 0) return;

    // ---- merge level 2: wave 0 merges lists 0-1 -> quarter-list
#pragma unroll
    for (int s = 0; s < NSLOT; ++s) m[s] = 0xFFFFFFFFu;
    for (int p2 = 0; p2 < 2; ++p2) {
#pragma unroll
        for (int s = 0; s < NSLOT; ++s) {
            unsigned key = keysh[p2 * NSLOT + s][lane];
#pragma unroll
            for (int t = NSLOT - 1; t >= 1; --t) m[t] = med3u(key, m[t - 1], m[t]);
            m[0] = min(key, m[0]);
        }
    }
    unsigned* myh = quarterkeys + (size_t)(g * NPAR + par) * NSLOT * 64;
#pragma unroll
    for (int s = 0; s < NSLOT; ++s) myh[s * 64 + lane] = m[s];
}

// f64 stats over a 16-neighbor set (slot indices into spts) — validated r5-r17.
__device__ void knn_stats(const float4* __restrict__ spts,
                          double qx, double qy, double qz,
                          const int* idx, const float* d2s,
                          double* den_out, double* lin_out) {
    double sx = 0, sy = 0, sz = 0;
    double sxx = 0, syy = 0, szz = 0, sxy = 0, sxz = 0, syz = 0;
    double dsum = 0;
#pragma unroll
    for (int s = 0; s < KNN; ++s) {
        float4 cp = spts[idx[s]];
        double ax = (double)cp.x - qx;
        double ay = (double)cp.y - qy;
        double az = (double)cp.z - qz;
        sx += ax; sy += ay; sz += az;
        sxx += ax * ax; syy += ay * ay; szz += az * az;
        sxy += ax * ay; sxz += ax * az; syz += ay * az;
        dsum += (double)sqrtf(d2s[s]);
    }
    const double invK  = 1.0 / KNN;
    const double invK1 = 1.0 / (KNN - 1);
    double mxx = sx * invK, myy = sy * invK, mzz = sz * invK;
    double cxx = (sxx - (double)KNN * mxx * mxx) * invK1;
    double cyy = (syy - (double)KNN * myy * myy) * invK1;
    double czz = (szz - (double)KNN * mzz * mzz) * invK1;
    double cxy = (sxy - (double)KNN * mxx * myy) * invK1;
    double cxz = (sxz - (double)KNN * mxx * mzz) * invK1;
    double cyz = (syz - (double)KNN * myy * mzz) * invK1;

    double T  = cxx + cyy + czz;
    double qq = T / 3.0;
    double b00 = cxx - qq, b11 = cyy - qq, b22 = czz - qq;
    double p2 = b00 * b00 + b11 * b11 + b22 * b22
              + 2.0 * (cxy * cxy + cxz * cxz + cyz * cyz);
    double lmax;
    if (p2 <= 1e-30) {
        lmax = qq;
    } else {
        double p = sqrt(p2 / 6.0);
        double detB = b00 * (b11 * b22 - cyz * cyz)
                    - cxy * (cxy * b22 - cyz * cxz)
                    + cxz * (cxy * cyz - b11 * cxz);
        double r = detB / (2.0 * p * p * p);
        r = fmin(1.0, fmax(-1.0, r));
        double phi = acos(r) / 3.0;
        lmax = qq + 2.0 * p * cos(phi);
    }
    *lin_out = (2.0 * lmax - T) / (T + 1e-6);
    *den_out = 1.0 / (dsum * invK + 1e-6);
}

// ---------------------------------------------------------------------------
// Finalize: 320 blocks x 64 (spreads over all 256 CUs). Merge the four
// quarter-lists, coverage check + rare rescan, slot-keyed exact re-rank,
// ambiguity-averaged f64 stats, head.
// ---------------------------------------------------------------------------
__global__ __launch_bounds__(64) void knn_finalize(
    const float4* __restrict__ spts, const int* __restrict__ sidx,
    const int* __restrict__ start,   const unsigned* __restrict__ quarterkeys,
    const float* __restrict__ h_ws,  const float* __restrict__ gamma,
    const float* __restrict__ beta,  const float* __restrict__ w2,
    const float* __restrict__ b2,    const float* __restrict__ mustats,
    float* __restrict__ out) {
    const int lane = threadIdx.x;
    const int g    = blockIdx.x;
    const int slot = g * 64 + lane;
    const float4 qp = spts[slot];
    const int ix = min(GH - 1, max(0, (int)(qp.x * (float)GH)));
    const int iy = min(GH - 1, max(0, (int)(qp.y * (float)GH)));
    const int iz = min(GH - 1, max(0, (int)(qp.z * (float)GH)));

    unsigned m[NSLOT];
#pragma unroll
    for (int s = 0; s < NSLOT; ++s) m[s] = 0xFFFFFFFFu;
    for (int par = 0; par < NPAR; ++par) {
        const unsigned* ph = quarterkeys + (size_t)(g * NPAR + par) * NSLOT * 64;
#pragma unroll
        for (int s = 0; s < NSLOT; ++s) {
            unsigned key = ph[s * 64 + lane];
#pragma unroll
            for (int t = NSLOT - 1; t >= 1; --t) m[t] = med3u(key, m[t - 1], m[t]);
            m[0] = min(key, m[0]);
        }
    }

    // ---- coverage check; rare per-lane expansion rescan (full stride)
    const float h = 1.0f / (float)GH;
    int rho = RHO0;
    for (;;) {
        float b16f = __uint_as_float(m[16] & 0xFFFF8000u);  // NaN if unfilled
        float cov  = (float)(rho * rho) * (h * h);
        bool ok = (fmaf(b16f, 0.00390625f, b16f) + 1e-6f) <= cov;
        if (__all(ok) || rho >= GH - 1) break;
        ++rho;
        if (!ok) {
#pragma unroll
            for (int s = 0; s < NSLOT; ++s) m[s] = 0xFFFFFFFFu;
            const int zlo = max(0, iz - rho), zhi = min(GH - 1, iz + rho);
            const int ylo = max(0, iy - rho), yhi = min(GH - 1, iy + rho);
            const int xlo = max(0, ix - rho), xhi = min(GH - 1, ix + rho);
            for (int cz = zlo; cz <= zhi; ++cz)
                for (int cy = ylo; cy <= yhi; ++cy) {
                    const int rb = (cz * GH + cy) * GH;
                    scan_range<1>(spts, start[rb + xlo], start[rb + xhi + 1],
                                  qp, slot, m);
                }
        }
    }

    // ---- exact re-rank: top KNN+1 u64 keys (full d2 bits << 32 | SLOT index)
    unsigned long long gk[KNN + 1];
#pragma unroll
    for (int s = 0; s < KNN + 1; ++s) gk[s] = ~0ull;
#pragma unroll
    for (int s = 0; s < NSLOT; ++s) {
        unsigned bs = m[s];
        int cs = min((int)(bs & 0x7FFFu), NPTS - 1);
        float4 cp = spts[cs];
        float d2 = ref_d2(qp.x, qp.y, qp.z, qp.w, cp.x, cp.y, cp.z, cp.w);
        unsigned long long kk =
            ((unsigned long long)__float_as_uint(d2) << 32) | (unsigned)cs;
        if (bs == 0xFFFFFFFFu) kk = ~0ull;
#pragma unroll
        for (int t = KNN; t >= 1; --t) {
            unsigned long long mn = (kk < gk[t]) ? kk : gk[t];
            gk[t] = (gk[t - 1] > mn) ? gk[t - 1] : mn;
        }
        gk[0] = (kk < gk[0]) ? kk : gk[0];
    }

    int   idxA[KNN];
    float d2A[KNN];
#pragma unroll
    for (int s = 0; s < KNN; ++s) {
        idxA[s] = (int)(gk[s] & 0xFFFFFFFFull);
        d2A[s]  = __uint_as_float((unsigned)(gk[s] >> 32));
    }
    float d16 = d2A[KNN - 1];
    float d17 = __uint_as_float((unsigned)(gk[KNN] >> 32));
    bool amb = (__fsub_rn(d17, d16) <= AMB_EPS);

    const double qx = (double)qp.x, qy = (double)qp.y, qz = (double)qp.z;
    double denA, linA;
    knn_stats(spts, qx, qy, qz, idxA, d2A, &denA, &linA);
    double den = denA, lin_d = linA;
    if (amb) {
        idxA[KNN - 1] = (int)(gk[KNN] & 0xFFFFFFFFull);
        d2A[KNN - 1]  = d17;
        double denB, linB;
        knn_stats(spts, qx, qy, qz, idxA, d2A, &denB, &linB);
        den = 0.5 * (denA + denB);
        lin_d = 0.5 * (linA + linB);
    }
    float dens = (float)den;
    float lin  = (float)lin_d;

    // ---- per-point head from precomputed h: BN + ReLU + GEMV + softmax
    const int qi = sidx[slot];
    float hh[NCH];
    const float4* h4 = reinterpret_cast<const float4*>(h_ws + (size_t)qi * NCH);
#pragma unroll
    for (int j4 = 0; j4 < NCH / 4; ++j4) {
        float4 v = h4[j4];
        hh[j4 * 4 + 0] = v.x; hh[j4 * 4 + 1] = v.y;
        hh[j4 * 4 + 2] = v.z; hh[j4 * 4 + 3] = v.w;
    }
    float l0 = b2[0], l1 = b2[1], l2 = b2[2];
#pragma unroll
    for (int j = 0; j < NCH; ++j) {
        float xn = (hh[j] - mustats[j]) * mustats[NCH + j] * gamma[j] + beta[j];
        xn = fmaxf(xn, 0.f);
        l0 = fmaf(xn, w2[j * 3 + 0], l0);
        l1 = fmaf(xn, w2[j * 3 + 1], l1);
        l2 = fmaf(xn, w2[j * 3 + 2], l2);
    }
    float mx = fmaxf(l0, fmaxf(l1, l2));
    float e0 = expf(l0 - mx), e1 = expf(l1 - mx), e2 = expf(l2 - mx);
    float is = 1.f / (e0 + e1 + e2);
    float p0 = e0 * is, p1 = e1 * is, p2v = e2 * is;

    float tower = (dens * 2.f + p0) * (1.f / 3.f);
    float back  = (fmaxf(1.f - lin, 1.f - dens) + p1) * (1.f / 3.f);
    float line  = (lin * 2.f + p2v) * (1.f / 3.f);
    float gxy = fmaf(tower, 0.05f, fmaf(back, 0.20f, fmaf(line, 0.10f, 1e-6f)));
    float gz  = fmaf(tower, 0.05f, fmaf(back, 0.20f, fmaf(line, 0.50f, 1e-6f)));
    out[3 * qi + 0] = gxy;
    out[3 * qi + 1] = gxy;
    out[3 * qi + 2] = gz;
}

extern "C" void kernel_launch(void* const* d_in, const int* in_sizes, int n_in,
                              void* d_out, int out_size, void* d_ws, size_t ws_size,
                              hipStream_t stream) {
    const float* feat  = (const float*)d_in[0];
    const float* coord = (const float*)d_in[1];
    // d_in[2] = batch (all zeros) — unused
    const float* w1    = (const float*)d_in[3];
    const float* b1    = (const float*)d_in[4];
    const float* gamma = (const float*)d_in[5];
    const float* beta  = (const float*)d_in[6];
    const float* w2    = (const float*)d_in[7];
    const float* b2    = (const float*)d_in[8];
    float* out = (float*)d_out;

    // workspace layout (~10.4 MB); cnt/cursor contiguous, zeroed by zero_cells
    float4* pts4   = (float4*)d_ws;                     // NPTS
    float4* spts   = pts4 + NPTS;                       // NPTS
    int* sidx      = (int*)(spts + NPTS);               // NPTS
    int* pcell     = sidx + NPTS;                       // NPTS
    int* cnt       = pcell + NPTS;                      // NCELL
    int* cursor    = cnt + NCELL;                       // NCELL
    int* startArr  = cursor + NCELL;                    // NCELL+1 (+pad)
    unsigned* quarterkeys = (unsigned*)(startArr + NCELL + 8); // NPAR*NGRP*NSLOT*64
    float* partials  = (float*)(quarterkeys + (size_t)NPAR * NGRP * NSLOT * 64);
    float* mustats   = partials + MLPBLK * 64;          // 64
    float* h_ws      = mustats + 64;                    // NPTS*NCH

    zero_cells<<<(2 * NCELL) / 256, 256, 0, stream>>>(cnt);
    prep_mlp<<<NBLK + MLPGRID, 256, 0, stream>>>(coord, pts4, pcell, cnt,
                                                 feat, w1, b1, h_ws, partials);
    scatter_pref<<<NBLK + 1, 256, 0, stream>>>(pts4, pcell, cnt, cursor,
                                               spts, sidx, partials, mustats,
                                               startArr);
    knn_scan<<<NPAR * NGRP, 256, 0, stream>>>(spts, startArr, quarterkeys);
    knn_finalize<<<NGRP, 64, 0, stream>>>(spts, sidx, startArr, quarterkeys,
                                          h_ws, gamma, beta, w2, b2, mustats,
                                          out);
}